// Round 7
// baseline (284.857 us; speedup 1.0000x reference)
//
#include <hip/hip_runtime.h>
#include <hip/hip_bf16.h>
#include <hip/hip_cooperative_groups.h>

namespace cg = cooperative_groups;

// Problem constants (fixed by setup_inputs)
constexpr int B = 512;   // batch
constexpr int D = 4096;  // D_vis
constexpr int E = 1024;  // embed dim
constexpr int N = 512;   // negatives

typedef __attribute__((ext_vector_type(8))) short bf16x8;   // 8 bf16 = 4 VGPRs
typedef __attribute__((ext_vector_type(4))) float f32x4;
typedef float v2f __attribute__((ext_vector_type(2)));

typedef __attribute__((address_space(3))) void lds_void;
typedef const __attribute__((address_space(1))) void gbl_void;

__device__ __forceinline__ unsigned short f2bf(float f) {
    __hip_bfloat16 h = __float2bfloat16(f);   // RTNE
    return *reinterpret_cast<unsigned short*>(&h);
}

// ===========================================================================
// MEGA KERNEL (cooperative): 256 blocks x 256 threads, 1 block/CU guaranteed
// (LDS 49152 B -> 3/CU by LDS; VGPR<=256 -> 2/CU; co-residency margin 2x).
//  P0 cvt f32->bf16   P1 gemm (KS=8; 1024 waves x 2 tasks, per-wave
//  global_load_lds dbuf pipeline)   P2 reduce+bias -> emb
//  P3 neg partials (64b x 64n tile fixed per block, accumulate 4 e-chunks)
//  P4 final reduce + sqrt + positives
// ===========================================================================
constexpr int KS = 8;           // GEMM K-split
constexpr int KC = D / KS;      // 512
constexpr int NSTEP = KC / 32;  // 16
constexpr int EC = 64;          // P3 e-chunk
constexpr int LDW = EC + 2;     // 66
constexpr int NPLANE = 4;       // pn planes

__global__ __launch_bounds__(256, 2) void mega(
    const float* __restrict__ vf,     // [B, D]
    const float* __restrict__ p_lfs,  // [B, E]
    const float* __restrict__ n_lfs,  // [N, E]
    const float* __restrict__ W,      // [E, D]
    const float* __restrict__ bias,   // [E]
    float* __restrict__ out,          // [B, 1+N]
    char* __restrict__ ws)
{
    // ws: pg [0,16MB) | vfB [16,20) | WB [20,28) | emb [28,30)
    //     pn [0,4MB) overlays pg (pg dead after P2)
    float*          pg  = (float*)ws;
    float*          pn  = (float*)ws;
    unsigned short* vfB = (unsigned short*)(ws + ((size_t)16 << 20));
    unsigned short* WB  = (unsigned short*)(ws + ((size_t)20 << 20));
    float*          emb = (float*)(ws + ((size_t)28 << 20));

    __shared__ __align__(16) char smem[49152];

    const int t   = threadIdx.x;
    const int bid = blockIdx.x;
    const int g   = bid * 256 + t;          // [0, 65536)
    cg::grid_group grid = cg::this_grid();

    // ---------------- P0: f32 -> bf16 (786432 8-elem chunks) ---------------
    #pragma unroll
    for (int k = 0; k < 12; ++k) {
        const int c = g + k * 65536;
        const float* src;
        unsigned short* dst;
        int i;
        if (c < 262144) { src = vf; dst = vfB; i = c * 8; }
        else            { src = W;  dst = WB;  i = (c - 262144) * 8; }
        float4 v0 = *(const float4*)(src + i);
        float4 v1 = *(const float4*)(src + i + 4);
        bf16x8 o;
        o[0] = (short)f2bf(v0.x); o[1] = (short)f2bf(v0.y);
        o[2] = (short)f2bf(v0.z); o[3] = (short)f2bf(v0.w);
        o[4] = (short)f2bf(v1.x); o[5] = (short)f2bf(v1.y);
        o[6] = (short)f2bf(v1.z); o[7] = (short)f2bf(v1.w);
        *(bf16x8*)(dst + i) = o;
    }

    grid.sync();

    // ---------------- P1: GEMM 64(m)x32(n) tile per wave-task, 2 tasks -----
    {
        const int w = t >> 6;
        const int L = t & 63;
        char* base = smem + w * 12288;   // A: [0,8K) 2x4KB, B: [8K,12K) 2x2KB

        const int subrow = L >> 2;                                  // 0..15
        const int qstg = (L & 3) ^ ((L >> 2) & 3) ^ ((L >> 4) & 3);
        const int r16 = L & 15;
        const int quad = L >> 4;
        const int swz = quad ^ (r16 & 3) ^ ((r16 >> 2) & 3);
        const int aoff = r16 * 64 + swz * 16;

        #pragma unroll 1
        for (int pass = 0; pass < 2; ++pass) {
            const int task = (bid * 4 + w) + pass * 1024;   // [0,2048)
            const int n0 = (task & 31) * 32;
            const int m0 = ((task >> 5) & 7) * 64;
            const int ks = task >> 8;
            const int kbeg = ks * KC;

            const unsigned short* aSrc[4];
            const unsigned short* bSrc[2];
            #pragma unroll
            for (int c = 0; c < 4; ++c)
                aSrc[c] = vfB + (size_t)(m0 + c * 16 + subrow) * D + kbeg + qstg * 8;
            #pragma unroll
            for (int c = 0; c < 2; ++c)
                bSrc[c] = WB  + (size_t)(n0 + c * 16 + subrow) * D + kbeg + qstg * 8;

            auto issue = [&](int step, int buf) {
                const size_t koff = (size_t)step * 32;
                #pragma unroll
                for (int c = 0; c < 4; ++c)
                    __builtin_amdgcn_global_load_lds(
                        (gbl_void*)(aSrc[c] + koff),
                        (lds_void*)(base + buf * 4096 + c * 1024), 16, 0, 0);
                #pragma unroll
                for (int c = 0; c < 2; ++c)
                    __builtin_amdgcn_global_load_lds(
                        (gbl_void*)(bSrc[c] + koff),
                        (lds_void*)(base + 8192 + buf * 2048 + c * 1024), 16, 0, 0);
            };

            f32x4 acc[4][2] = {};

            issue(0, 0);
            issue(1, 1);

            #pragma unroll 1
            for (int s = 0; s < NSTEP; ++s) {
                const int buf = s & 1;
                if (s == NSTEP - 1) __builtin_amdgcn_s_waitcnt(0x0F70); // vmcnt(0)
                else                __builtin_amdgcn_s_waitcnt(0x0F76); // vmcnt(6)

                bf16x8 af[4], bfr[2];
                #pragma unroll
                for (int i = 0; i < 4; ++i)
                    af[i] = *(const bf16x8*)(base + buf * 4096 + i * 1024 + aoff);
                #pragma unroll
                for (int j = 0; j < 2; ++j)
                    bfr[j] = *(const bf16x8*)(base + 8192 + buf * 2048 + j * 1024 + aoff);

                #pragma unroll
                for (int i = 0; i < 4; ++i)
                    #pragma unroll
                    for (int j = 0; j < 2; ++j)
                        acc[i][j] = __builtin_amdgcn_mfma_f32_16x16x32_bf16(
                            af[i], bfr[j], acc[i][j], 0, 0, 0);

                if (s + 2 < NSTEP) issue(s + 2, buf);
            }

            float* po = pg + (size_t)ks * B * E;
            #pragma unroll
            for (int j = 0; j < 2; ++j) {
                const int col = n0 + j * 16 + r16;
                #pragma unroll
                for (int i = 0; i < 4; ++i) {
                    const int row = m0 + i * 16 + quad * 4;
                    #pragma unroll
                    for (int r = 0; r < 4; ++r)
                        po[(size_t)(row + r) * E + col] = acc[i][j][r];
                }
            }
        }
    }

    grid.sync();

    // ---------------- P2: emb = sum_ks pg + bias (exact cover x2) ----------
    #pragma unroll
    for (int k = 0; k < 2; ++k) {
        const int idx = (g + k * 65536) * 4;    // [0, 524288) elements
        const int col = idx & (E - 1);
        float4 s = *(const float4*)(bias + col);
        #pragma unroll
        for (int z = 0; z < KS; ++z) {
            float4 p = *(const float4*)(pg + (size_t)z * B * E + idx);
            s.x += p.x; s.y += p.y; s.z += p.z; s.w += p.w;
        }
        *(float4*)(emb + idx) = s;
    }

    grid.sync();

    // ---------------- P3: neg partials; (b0,n0) fixed, 4 e-chunks summed ---
    {
        float* eS = (float*)smem;          // [64*66]
        float* nS = eS + 64 * LDW;         // [64*66]  total 33792 B

        const int n0 = (bid & 7) * 64;
        const int b0 = ((bid >> 3) & 7) * 64;
        const int c0 = bid >> 6;           // plane [0,4)

        const int row = t >> 2;            // 0..63
        const int cb  = (t & 3) * 16;      // 0,16,32,48
        const int ty = t >> 4;             // 0..15
        const int tx = t & 15;             // 0..15

        const v2f z = {0.f, 0.f};
        v2f acc[4][4] = {{z,z,z,z},{z,z,z,z},{z,z,z,z},{z,z,z,z}};

        #pragma unroll 1
        for (int p = 0; p < 4; ++p) {
            const int e0 = (c0 + 4 * p) * EC;
            __syncthreads();
            {
                const float* ep = emb   + (size_t)(b0 + row) * E + e0 + cb;
                const float* np = n_lfs + (size_t)(n0 + row) * E + e0 + cb;
                float* ed = &eS[row * LDW + cb];
                float* nd = &nS[row * LDW + cb];
                #pragma unroll
                for (int q = 0; q < 4; ++q) {
                    float4 v  = *(const float4*)(ep + q * 4);
                    float4 wv = *(const float4*)(np + q * 4);
                    *(v2f*)(ed + q * 4)     = (v2f){v.x, v.y};
                    *(v2f*)(ed + q * 4 + 2) = (v2f){v.z, v.w};
                    *(v2f*)(nd + q * 4)     = (v2f){wv.x, wv.y};
                    *(v2f*)(nd + q * 4 + 2) = (v2f){wv.z, wv.w};
                }
            }
            __syncthreads();

            #pragma unroll 4
            for (int e = 0; e < EC; e += 2) {
                v2f a[4], c[4];
                #pragma unroll
                for (int r = 0; r < 4; ++r)
                    a[r] = *(const v2f*)&eS[(ty + 16 * r) * LDW + e];
                #pragma unroll
                for (int q = 0; q < 4; ++q)
                    c[q] = *(const v2f*)&nS[(tx + 16 * q) * LDW + e];
                #pragma unroll
                for (int r = 0; r < 4; ++r)
                    #pragma unroll
                    for (int q = 0; q < 4; ++q) {
                        v2f d = c[q] - a[r];
                        d = __builtin_elementwise_max(d, z);
                        acc[r][q] = __builtin_elementwise_fma(d, d, acc[r][q]);
                    }
            }
        }

        float* po = pn + (size_t)c0 * B * N;
        #pragma unroll
        for (int r = 0; r < 4; ++r) {
            const size_t ob = (size_t)(b0 + ty + 16 * r) * N;
            #pragma unroll
            for (int q = 0; q < 4; ++q)
                po[ob + n0 + tx + 16 * q] = acc[r][q].x + acc[r][q].y;
        }
    }

    grid.sync();

    // ---------------- P4: final reduce + sqrt ------------------------------
    {
        const int i = g * 4;                 // [0, B*N)
        const int b = i >> 9;
        const int n = i & (N - 1);
        float4 s = {0.f, 0.f, 0.f, 0.f};
        #pragma unroll
        for (int z = 0; z < NPLANE; ++z) {
            float4 p = *(const float4*)(pn + (size_t)z * B * N + i);
            s.x += p.x; s.y += p.y; s.z += p.z; s.w += p.w;
        }
        float* o = out + (size_t)b * 513 + 1 + n;
        o[0] = -sqrtf(s.x); o[1] = -sqrtf(s.y);
        o[2] = -sqrtf(s.z); o[3] = -sqrtf(s.w);

        if (bid < 16) {
            const int b0 = bid * 32;
            const int r = t >> 3;
            const int gq = t & 7;
            const float* pr = p_lfs + (size_t)(b0 + r) * E;
            const float* er = emb   + (size_t)(b0 + r) * E;
            float acc = 0.f;
            for (int e = gq * 4; e < E; e += 32) {
                float4 p = *(const float4*)(pr + e);
                float4 v = *(const float4*)(er + e);
                float d;
                d = p.x - v.x; d = fmaxf(d, 0.f); acc = fmaf(d, d, acc);
                d = p.y - v.y; d = fmaxf(d, 0.f); acc = fmaf(d, d, acc);
                d = p.z - v.z; d = fmaxf(d, 0.f); acc = fmaf(d, d, acc);
                d = p.w - v.w; d = fmaxf(d, 0.f); acc = fmaf(d, d, acc);
            }
            #pragma unroll
            for (int off = 4; off; off >>= 1) acc += __shfl_down(acc, off, 8);
            if (gq == 0) out[(size_t)(b0 + r) * 513] = -sqrtf(acc);
        }
    }
}

// ===========================================================================
// FALLBACK PATH — verified round-5 pipeline (runs only if coop launch fails)
// ws: pg/pn [0,8MB) | vfB [8,12) | WB [12,20) | emb [20,22)
// ===========================================================================
constexpr int FKS = 4;
constexpr int FKC = D / FKS;
constexpr int FNS = FKC / 32;
constexpr int FES = 8;
constexpr int FEC = E / FES;

__global__ __launch_bounds__(256) void cvt_all(
    const float* __restrict__ vf, const float* __restrict__ W,
    unsigned short* __restrict__ vfB, unsigned short* __restrict__ WB)
{
    const int bid = blockIdx.x;
    const float* src;
    unsigned short* dst;
    int i;
    if (bid < 1024) { src = vf; dst = vfB; i = (bid * 256 + threadIdx.x) * 8; }
    else           { src = W;  dst = WB;  i = ((bid - 1024) * 256 + threadIdx.x) * 8; }
    float4 v0 = *(const float4*)(src + i);
    float4 v1 = *(const float4*)(src + i + 4);
    bf16x8 o;
    o[0] = (short)f2bf(v0.x); o[1] = (short)f2bf(v0.y);
    o[2] = (short)f2bf(v0.z); o[3] = (short)f2bf(v0.w);
    o[4] = (short)f2bf(v1.x); o[5] = (short)f2bf(v1.y);
    o[6] = (short)f2bf(v1.z); o[7] = (short)f2bf(v1.w);
    *(bf16x8*)(dst + i) = o;
}

__global__ __launch_bounds__(64) void gemm_lds(
    const unsigned short* __restrict__ vf,
    const unsigned short* __restrict__ W,
    float* __restrict__ part)
{
    __shared__ unsigned short sA[2][2048];
    __shared__ unsigned short sB[2][2048];

    const int L  = threadIdx.x;
    const int n0 = blockIdx.x * 64;
    const int m0 = blockIdx.y * 64;
    const int ks = blockIdx.z;

    const int subrow = L >> 2;
    const int qstg = (L & 3) ^ ((L >> 2) & 3) ^ ((L >> 4) & 3);
    const int kbeg = ks * FKC;
    const unsigned short* aSrc[4];
    const unsigned short* bSrc[4];
    #pragma unroll
    for (int c = 0; c < 4; ++c) {
        aSrc[c] = vf + (size_t)(m0 + c * 16 + subrow) * D + kbeg + qstg * 8;
        bSrc[c] = W  + (size_t)(n0 + c * 16 + subrow) * D + kbeg + qstg * 8;
    }

    const int r16 = L & 15;
    const int quad = L >> 4;
    const int swz = quad ^ (r16 & 3) ^ ((r16 >> 2) & 3);
    const int aoff = r16 * 64 + swz * 16;

    f32x4 acc[4][4] = {};

    auto issue = [&](int step, int buf) {
        const size_t koff = (size_t)step * 32;
        #pragma unroll
        for (int c = 0; c < 4; ++c) {
            __builtin_amdgcn_global_load_lds(
                (gbl_void*)(aSrc[c] + koff),
                (lds_void*)((char*)&sA[buf][0] + c * 1024), 16, 0, 0);
            __builtin_amdgcn_global_load_lds(
                (gbl_void*)(bSrc[c] + koff),
                (lds_void*)((char*)&sB[buf][0] + c * 1024), 16, 0, 0);
        }
    };

    issue(0, 0);
    issue(1, 1);

    #pragma unroll 1
    for (int s = 0; s < FNS; ++s) {
        const int buf = s & 1;
        if (s == FNS - 1) __builtin_amdgcn_s_waitcnt(0x0F70);
        else              __builtin_amdgcn_s_waitcnt(0x0F78);

        bf16x8 af[4], bf_[4];
        #pragma unroll
        for (int i = 0; i < 4; ++i)
            af[i] = *(const bf16x8*)((const char*)&sA[buf][0] + i * 1024 + aoff);
        #pragma unroll
        for (int j = 0; j < 4; ++j)
            bf_[j] = *(const bf16x8*)((const char*)&sB[buf][0] + j * 1024 + aoff);

        #pragma unroll
        for (int i = 0; i < 4; ++i)
            #pragma unroll
            for (int j = 0; j < 4; ++j)
                acc[i][j] = __builtin_amdgcn_mfma_f32_16x16x32_bf16(
                    af[i], bf_[j], acc[i][j], 0, 0, 0);

        if (s + 2 < FNS) issue(s + 2, buf);
    }

    float* po = part + (size_t)ks * B * E;
    #pragma unroll
    for (int j = 0; j < 4; ++j) {
        const int col = n0 + j * 16 + r16;
        #pragma unroll
        for (int i = 0; i < 4; ++i) {
            const int row = m0 + i * 16 + quad * 4;
            #pragma unroll
            for (int r = 0; r < 4; ++r)
                po[(size_t)(row + r) * E + col] = acc[i][j][r];
        }
    }
}

__global__ __launch_bounds__(256) void reduce_emb(
    const float* __restrict__ part, const float* __restrict__ bias,
    float* __restrict__ emb)
{
    const int idx = (blockIdx.x * 256 + threadIdx.x) * 4;
    const int col = idx & (E - 1);
    float4 s = *(const float4*)(bias + col);
    #pragma unroll
    for (int ks = 0; ks < FKS; ++ks) {
        float4 p = *(const float4*)(part + (size_t)ks * B * E + idx);
        s.x += p.x; s.y += p.y; s.z += p.z; s.w += p.w;
    }
    *(float4*)(emb + idx) = s;
}

__global__ __launch_bounds__(256, 2) void scores_part(
    const float* __restrict__ emb,
    const float* __restrict__ n_lfs,
    float* __restrict__ pn)
{
    constexpr int W2 = FEC + 2;
    __shared__ float eS[64 * W2];
    __shared__ float nS[64 * W2];

    const int t  = threadIdx.x;
    const int n0 = blockIdx.x * 64;
    const int b0 = blockIdx.y * 64;
    const int e0 = blockIdx.z * FEC;

    {
        const int row = t >> 2;
        const int cb  = (t & 3) * 32;
        const float* ep = emb   + (size_t)(b0 + row) * E + e0 + cb;
        const float* np = n_lfs + (size_t)(n0 + row) * E + e0 + cb;
        float* ed = &eS[row * W2 + cb];
        float* nd = &nS[row * W2 + cb];
        #pragma unroll
        for (int q = 0; q < 8; ++q) {
            float4 v = *(const float4*)(ep + q * 4);
            float4 w = *(const float4*)(np + q * 4);
            *(v2f*)(ed + q * 4)     = (v2f){v.x, v.y};
            *(v2f*)(ed + q * 4 + 2) = (v2f){v.z, v.w};
            *(v2f*)(nd + q * 4)     = (v2f){w.x, w.y};
            *(v2f*)(nd + q * 4 + 2) = (v2f){w.z, w.w};
        }
    }
    __syncthreads();

    const int ty = t >> 4;
    const int tx = t & 15;

    const v2f z = {0.f, 0.f};
    v2f acc[4][4] = {{z,z,z,z},{z,z,z,z},{z,z,z,z},{z,z,z,z}};

    #pragma unroll 4
    for (int e = 0; e < FEC; e += 2) {
        v2f a[4], c[4];
        #pragma unroll
        for (int r = 0; r < 4; ++r)
            a[r] = *(const v2f*)&eS[(ty + 16 * r) * W2 + e];
        #pragma unroll
        for (int q = 0; q < 4; ++q)
            c[q] = *(const v2f*)&nS[(tx + 16 * q) * W2 + e];
        #pragma unroll
        for (int r = 0; r < 4; ++r)
            #pragma unroll
            for (int q = 0; q < 4; ++q) {
                v2f d = c[q] - a[r];
                d = __builtin_elementwise_max(d, z);
                acc[r][q] = __builtin_elementwise_fma(d, d, acc[r][q]);
            }
    }

    float* po = pn + (size_t)blockIdx.z * B * N;
    #pragma unroll
    for (int r = 0; r < 4; ++r) {
        const size_t ob = (size_t)(b0 + ty + 16 * r) * N;
        #pragma unroll
        for (int q = 0; q < 4; ++q)
            po[ob + n0 + tx + 16 * q] = acc[r][q].x + acc[r][q].y;
    }
}

__global__ __launch_bounds__(256) void scores_final(
    const float* __restrict__ pn,
    const float* __restrict__ emb,
    const float* __restrict__ p_lfs,
    float* __restrict__ out)
{
    const int t = threadIdx.x;
    if (blockIdx.x < 1024) {
        const int i = blockIdx.x * 256 + t;
        const int b = i >> 9;
        const int n = i & (N - 1);
        float s = 0.f;
        #pragma unroll
        for (int z = 0; z < FES; ++z)
            s += pn[(size_t)z * B * N + i];
        out[(size_t)b * 513 + 1 + n] = -sqrtf(s);
        return;
    }
    const int b0 = (blockIdx.x - 1024) * 32;
    const int r = t >> 3;
    const int g = t & 7;
    const float* pr = p_lfs + (size_t)(b0 + r) * E;
    const float* er = emb   + (size_t)(b0 + r) * E;
    float acc = 0.f;
    for (int e = g * 4; e < E; e += 32) {
        float4 p = *(const float4*)(pr + e);
        float4 v = *(const float4*)(er + e);
        float d;
        d = p.x - v.x; d = fmaxf(d, 0.f); acc = fmaf(d, d, acc);
        d = p.y - v.y; d = fmaxf(d, 0.f); acc = fmaf(d, d, acc);
        d = p.z - v.z; d = fmaxf(d, 0.f); acc = fmaf(d, d, acc);
        d = p.w - v.w; d = fmaxf(d, 0.f); acc = fmaf(d, d, acc);
    }
    #pragma unroll
    for (int off = 4; off; off >>= 1) acc += __shfl_down(acc, off, 8);
    if (g == 0) out[(size_t)(b0 + r) * 513] = -sqrtf(acc);
}

extern "C" void kernel_launch(void* const* d_in, const int* in_sizes, int n_in,
                              void* d_out, int out_size, void* d_ws, size_t ws_size,
                              hipStream_t stream) {
    const float* vf    = (const float*)d_in[0];  // [512,4096] f32
    const float* p_lfs = (const float*)d_in[1];  // [512,1024] f32
    const float* n_lfs = (const float*)d_in[2];  // [512,1024] f32
    const float* W     = (const float*)d_in[3];  // [1024,4096] f32
    const float* bias  = (const float*)d_in[4];  // [1024] f32
    float* out = (float*)d_out;                  // [512,513] f32
    char* ws   = (char*)d_ws;

    void* args[] = {(void*)&vf, (void*)&p_lfs, (void*)&n_lfs, (void*)&W,
                    (void*)&bias, (void*)&out, (void*)&ws};
    hipError_t err = hipLaunchCooperativeKernel((const void*)mega, dim3(256),
                                                dim3(256), args, 0, stream);
    if (err == hipSuccess) return;
    (void)hipGetLastError();  // clear sticky error; take verified fallback path

    // ---- fallback: round-5 five-kernel pipeline ----
    float*          pg  = (float*)ws;
    float*          pn  = (float*)ws;
    unsigned short* vfB = (unsigned short*)(ws + ((size_t)8 << 20));
    unsigned short* WB  = (unsigned short*)(ws + ((size_t)12 << 20));
    float*          emb = (float*)(ws + ((size_t)20 << 20));

    cvt_all<<<3072, 256, 0, stream>>>(vf, W, vfB, WB);
    dim3 g1(E / 64, B / 64, FKS);
    gemm_lds<<<g1, 64, 0, stream>>>(vfB, WB, pg);
    reduce_emb<<<(B * E) / 1024, 256, 0, stream>>>(pg, bias, emb);
    dim3 g3(N / 64, B / 64, FES);
    scores_part<<<g3, 256, 0, stream>>>(emb, n_lfs, pn);
    scores_final<<<1024 + B / 32, 256, 0, stream>>>(pn, emb, p_lfs, out);
}

// Round 8
// 219.522 us; speedup vs baseline: 1.2976x; 1.2976x over previous
//
#include <hip/hip_runtime.h>
#include <hip/hip_bf16.h>

// Problem constants (fixed by setup_inputs)
constexpr int B = 512;   // batch
constexpr int D = 4096;  // D_vis
constexpr int E = 1024;  // embed dim
constexpr int N = 512;   // negatives
constexpr int KS = 4;    // GEMM K-split factor
constexpr int KC = D / KS;      // 1024 K per split
constexpr int NSTEP = KC / 32;  // 32 k-steps
constexpr int ES = 8;    // scores E-split factor
constexpr int EC = E / ES;      // 128 e per scores block
constexpr int LDW = EC + 2;     // 130

typedef __attribute__((ext_vector_type(8))) short bf16x8;   // 8 bf16 = 4 VGPRs
typedef __attribute__((ext_vector_type(4))) float f32x4;
typedef float v2f __attribute__((ext_vector_type(2)));

typedef __attribute__((address_space(3))) void lds_void;
typedef const __attribute__((address_space(1))) void gbl_void;

__device__ __forceinline__ unsigned short f2bf(float f) {
    __hip_bfloat16 h = __float2bfloat16(f);   // RTNE
    return *reinterpret_cast<unsigned short*>(&h);
}

// ---------------------------------------------------------------------------
// Kernel 0: f32 -> bf16 convert for BOTH vf and W in one dispatch.
// ---------------------------------------------------------------------------
__global__ __launch_bounds__(256) void cvt_all(
    const float* __restrict__ vf, const float* __restrict__ W,
    unsigned short* __restrict__ vfB, unsigned short* __restrict__ WB)
{
    const int bid = blockIdx.x;
    const float* src;
    unsigned short* dst;
    int i;
    if (bid < 1024) { src = vf; dst = vfB; i = (bid * 256 + threadIdx.x) * 8; }
    else           { src = W;  dst = WB;  i = ((bid - 1024) * 256 + threadIdx.x) * 8; }
    float4 v0 = *(const float4*)(src + i);
    float4 v1 = *(const float4*)(src + i + 4);
    bf16x8 o;
    o[0] = (short)f2bf(v0.x); o[1] = (short)f2bf(v0.y);
    o[2] = (short)f2bf(v0.z); o[3] = (short)f2bf(v0.w);
    o[4] = (short)f2bf(v1.x); o[5] = (short)f2bf(v1.y);
    o[6] = (short)f2bf(v1.z); o[7] = (short)f2bf(v1.w);
    *(bf16x8*)(dst + i) = o;
}

// ---------------------------------------------------------------------------
// Kernel 1: K-split GEMM (round-5 proven). One wave/block, 64x64 tile, KS=4.
// grid (16,8,4) = 512 blocks = 2 blocks/CU. Per-wave global_load_lds dbuf.
// ---------------------------------------------------------------------------
__global__ __launch_bounds__(64) void gemm_lds(
    const unsigned short* __restrict__ vf,
    const unsigned short* __restrict__ W,
    float* __restrict__ part)                 // [KS, B, E] f32
{
    __shared__ unsigned short sA[2][2048];
    __shared__ unsigned short sB[2][2048];

    const int L  = threadIdx.x;
    const int n0 = blockIdx.x * 64;
    const int m0 = blockIdx.y * 64;
    const int ks = blockIdx.z;

    const int subrow = L >> 2;
    const int qstg = (L & 3) ^ ((L >> 2) & 3) ^ ((L >> 4) & 3);
    const int kbeg = ks * KC;
    const unsigned short* aSrc[4];
    const unsigned short* bSrc[4];
    #pragma unroll
    for (int c = 0; c < 4; ++c) {
        aSrc[c] = vf + (size_t)(m0 + c * 16 + subrow) * D + kbeg + qstg * 8;
        bSrc[c] = W  + (size_t)(n0 + c * 16 + subrow) * D + kbeg + qstg * 8;
    }

    const int r16 = L & 15;
    const int quad = L >> 4;
    const int swz = quad ^ (r16 & 3) ^ ((r16 >> 2) & 3);
    const int aoff = r16 * 64 + swz * 16;

    f32x4 acc[4][4] = {};

    auto issue = [&](int step, int buf) {
        const size_t koff = (size_t)step * 32;
        #pragma unroll
        for (int c = 0; c < 4; ++c) {
            __builtin_amdgcn_global_load_lds(
                (gbl_void*)(aSrc[c] + koff),
                (lds_void*)((char*)&sA[buf][0] + c * 1024), 16, 0, 0);
            __builtin_amdgcn_global_load_lds(
                (gbl_void*)(bSrc[c] + koff),
                (lds_void*)((char*)&sB[buf][0] + c * 1024), 16, 0, 0);
        }
    };

    issue(0, 0);
    issue(1, 1);

    #pragma unroll 1
    for (int s = 0; s < NSTEP; ++s) {
        const int buf = s & 1;
        if (s == NSTEP - 1) __builtin_amdgcn_s_waitcnt(0x0F70);  // vmcnt(0)
        else                __builtin_amdgcn_s_waitcnt(0x0F78);  // vmcnt(8)

        bf16x8 af[4], bf_[4];
        #pragma unroll
        for (int i = 0; i < 4; ++i)
            af[i] = *(const bf16x8*)((const char*)&sA[buf][0] + i * 1024 + aoff);
        #pragma unroll
        for (int j = 0; j < 4; ++j)
            bf_[j] = *(const bf16x8*)((const char*)&sB[buf][0] + j * 1024 + aoff);

        #pragma unroll
        for (int i = 0; i < 4; ++i)
            #pragma unroll
            for (int j = 0; j < 4; ++j)
                acc[i][j] = __builtin_amdgcn_mfma_f32_16x16x32_bf16(
                    af[i], bf_[j], acc[i][j], 0, 0, 0);

        if (s + 2 < NSTEP) issue(s + 2, buf);
    }

    float* po = part + (size_t)ks * B * E;
    #pragma unroll
    for (int j = 0; j < 4; ++j) {
        const int col = n0 + j * 16 + r16;
        #pragma unroll
        for (int i = 0; i < 4; ++i) {
            const int row = m0 + i * 16 + quad * 4;
            #pragma unroll
            for (int r = 0; r < 4; ++r)
                po[(size_t)(row + r) * E + col] = acc[i][j][r];
        }
    }
}

// ---------------------------------------------------------------------------
// Kernel 2: fused scores. grid (9, 8, 8) = 576 blocks, 256 thr.
//  x<8 : neg tile (n0,b0) x e-plane z. emb chunk computed INLINE from
//        pg (4 planes) + bias during staging (emb never materialized).
//        Plane partial -> pn[z]; 8th finisher block (device-scope ticket)
//        sums 8 planes -> out[b][1+n] = -sqrt(s).
//  x==8: pos partial (b0, z): pp[z][b] over its 128-e chunk; 8th finisher
//        sums -> out[b][0].
// Tickets: tk[0..63] neg tiles (b0i*8+n0i), tk[64..71] pos (b0i). Zeroed
// via hipMemsetAsync before each launch.
// ---------------------------------------------------------------------------
__global__ __launch_bounds__(256, 2) void scores_fused(
    const float* __restrict__ pg,     // [KS, B, E] f32
    const float* __restrict__ bias,   // [E]
    const float* __restrict__ n_lfs,  // [N, E]
    const float* __restrict__ p_lfs,  // [B, E]
    float* __restrict__ pn,           // [ES, B, N]
    float* __restrict__ pp,           // [ES, B]
    int* __restrict__ tk,             // [72]
    float* __restrict__ out)          // [B, 1+N]
{
    __shared__ float eS[64 * LDW];
    __shared__ float nS[64 * LDW];
    __shared__ int lastFlag;

    const int t   = threadIdx.x;
    const int b0i = blockIdx.y;
    const int z   = blockIdx.z;
    const int b0  = b0i * 64;
    const int e0  = z * EC;

    if (blockIdx.x == 8) {
        // ---------------- positive partials ----------------
        const int row = t >> 2;        // 0..63
        const int sub = t & 3;         // 4 threads/row, 32 e each
        const int b   = b0 + row;
        const int eb  = e0 + sub * 32;
        float acc = 0.f;
        #pragma unroll
        for (int q = 0; q < 8; ++q) {
            const int e = eb + q * 4;
            float4 s = *(const float4*)(bias + e);
            #pragma unroll
            for (int ks = 0; ks < KS; ++ks) {
                float4 p = *(const float4*)(pg + (size_t)ks * B * E + (size_t)b * E + e);
                s.x += p.x; s.y += p.y; s.z += p.z; s.w += p.w;
            }
            float4 p = *(const float4*)(p_lfs + (size_t)b * E + e);
            float d;
            d = p.x - s.x; d = fmaxf(d, 0.f); acc = fmaf(d, d, acc);
            d = p.y - s.y; d = fmaxf(d, 0.f); acc = fmaf(d, d, acc);
            d = p.z - s.z; d = fmaxf(d, 0.f); acc = fmaf(d, d, acc);
            d = p.w - s.w; d = fmaxf(d, 0.f); acc = fmaf(d, d, acc);
        }
        acc += __shfl_down(acc, 2, 4);
        acc += __shfl_down(acc, 1, 4);
        if (sub == 0) pp[z * B + b] = acc;

        __syncthreads();                 // drains vmem before barrier
        __threadfence();                 // release: pp visible device-wide
        if (t == 0) lastFlag = (atomicAdd(&tk[64 + b0i], 1) == ES - 1);
        __syncthreads();
        if (lastFlag) {
            __threadfence();             // acquire: see other planes
            if (t < 64) {
                const int b2 = b0 + t;
                float s = 0.f;
                #pragma unroll
                for (int zz = 0; zz < ES; ++zz) s += pp[zz * B + b2];
                out[(size_t)b2 * 513] = -sqrtf(s);
            }
        }
        return;
    }

    // ---------------- negative tile ----------------
    const int n0 = blockIdx.x * 64;
    {
        const int row = t >> 2;            // 0..63
        const int cb  = (t & 3) * 32;      // 0,32,64,96
        const float* np = n_lfs + (size_t)(n0 + row) * E + e0 + cb;
        const size_t ebase = (size_t)(b0 + row) * E + e0 + cb;
        float* ed = &eS[row * LDW + cb];
        float* nd = &nS[row * LDW + cb];
        #pragma unroll
        for (int q = 0; q < 8; ++q) {
            // emb chunk = bias + sum of 4 pg planes (inline reduce)
            float4 v = *(const float4*)(bias + ((ebase + q * 4) & (E - 1)));
            #pragma unroll
            for (int ks = 0; ks < KS; ++ks) {
                float4 p = *(const float4*)(pg + (size_t)ks * B * E + ebase + q * 4);
                v.x += p.x; v.y += p.y; v.z += p.z; v.w += p.w;
            }
            float4 wv = *(const float4*)(np + q * 4);
            *(v2f*)(ed + q * 4)     = (v2f){v.x, v.y};
            *(v2f*)(ed + q * 4 + 2) = (v2f){v.z, v.w};
            *(v2f*)(nd + q * 4)     = (v2f){wv.x, wv.y};
            *(v2f*)(nd + q * 4 + 2) = (v2f){wv.z, wv.w};
        }
    }
    __syncthreads();

    const int ty = t >> 4;   // 0..15 -> b rows ty+16r
    const int tx = t & 15;   // 0..15 -> n rows tx+16c

    const v2f zv = {0.f, 0.f};
    v2f acc[4][4] = {{zv,zv,zv,zv},{zv,zv,zv,zv},{zv,zv,zv,zv},{zv,zv,zv,zv}};

    #pragma unroll 4
    for (int e = 0; e < EC; e += 2) {
        v2f a[4], c[4];
        #pragma unroll
        for (int r = 0; r < 4; ++r)
            a[r] = *(const v2f*)&eS[(ty + 16 * r) * LDW + e];
        #pragma unroll
        for (int q = 0; q < 4; ++q)
            c[q] = *(const v2f*)&nS[(tx + 16 * q) * LDW + e];
        #pragma unroll
        for (int r = 0; r < 4; ++r)
            #pragma unroll
            for (int q = 0; q < 4; ++q) {
                v2f d = c[q] - a[r];
                d = __builtin_elementwise_max(d, zv);
                acc[r][q] = __builtin_elementwise_fma(d, d, acc[r][q]);
            }
    }

    float* po = pn + (size_t)z * B * N;
    #pragma unroll
    for (int r = 0; r < 4; ++r) {
        const size_t ob = (size_t)(b0 + ty + 16 * r) * N;
        #pragma unroll
        for (int q = 0; q < 4; ++q)
            po[ob + n0 + tx + 16 * q] = acc[r][q].x + acc[r][q].y;
    }

    __syncthreads();                 // all plane stores issued & drained
    __threadfence();                 // release
    if (t == 0) lastFlag = (atomicAdd(&tk[b0i * 8 + blockIdx.x], 1) == ES - 1);
    __syncthreads();
    if (lastFlag) {
        __threadfence();             // acquire
        #pragma unroll
        for (int r = 0; r < 4; ++r) {
            const int b = b0 + ty + 16 * r;
            #pragma unroll
            for (int q = 0; q < 4; ++q) {
                const int n = n0 + tx + 16 * q;
                float s = 0.f;
                #pragma unroll
                for (int zz = 0; zz < ES; ++zz)
                    s += pn[(size_t)zz * B * N + (size_t)b * N + n];
                out[(size_t)b * 513 + 1 + n] = -sqrtf(s);
            }
        }
    }
}

extern "C" void kernel_launch(void* const* d_in, const int* in_sizes, int n_in,
                              void* d_out, int out_size, void* d_ws, size_t ws_size,
                              hipStream_t stream) {
    const float* vf    = (const float*)d_in[0];  // [512,4096] f32
    const float* p_lfs = (const float*)d_in[1];  // [512,1024] f32
    const float* n_lfs = (const float*)d_in[2];  // [512,1024] f32
    const float* W     = (const float*)d_in[3];  // [1024,4096] f32
    const float* bias  = (const float*)d_in[4];  // [1024] f32
    float* out = (float*)d_out;                  // [512,513] f32

    // ws: pg [0,8MB) | pn [8,16MB) | pp [16MB,+16KB) | tk [17MB,+288B)
    //     vfB [18,22MB) | WB [22,30MB)   -- no overlays (pg live during scores)
    char* ws = (char*)d_ws;
    float*          pg  = (float*)ws;
    float*          pn  = (float*)(ws + ((size_t)8 << 20));
    float*          pp  = (float*)(ws + ((size_t)16 << 20));
    int*            tk  = (int*)  (ws + ((size_t)17 << 20));
    unsigned short* vfB = (unsigned short*)(ws + ((size_t)18 << 20));
    unsigned short* WB  = (unsigned short*)(ws + ((size_t)22 << 20));

    hipMemsetAsync(tk, 0, 72 * sizeof(int), stream);

    cvt_all<<<3072, 256, 0, stream>>>(vf, W, vfB, WB);

    dim3 g1(E / 64, B / 64, KS);   // (16, 8, 4) = 512 one-wave blocks
    gemm_lds<<<g1, 64, 0, stream>>>(vfB, WB, pg);

    dim3 g2(9, B / 64, ES);        // (9, 8, 8) = 576 blocks
    scores_fused<<<g2, 256, 0, stream>>>(pg, bias, n_lfs, p_lfs, pn, pp, tk, out);
}

// Round 9
// 202.019 us; speedup vs baseline: 1.4100x; 1.0866x over previous
//
#include <hip/hip_runtime.h>
#include <hip/hip_bf16.h>

// Problem constants (fixed by setup_inputs)
constexpr int B = 512;   // batch
constexpr int D = 4096;  // D_vis
constexpr int E = 1024;  // embed dim
constexpr int N = 512;   // negatives
constexpr int KS = 4;    // GEMM K-split factor
constexpr int KC = D / KS;      // 1024 K per split
constexpr int NSTEP = KC / 32;  // 32 k-steps
constexpr int ES = 8;    // scores E-split factor
constexpr int EC = E / ES;      // 128 e per scores block
constexpr int LDW = EC + 2;     // 130

typedef __attribute__((ext_vector_type(8))) short bf16x8;   // 8 bf16 = 4 VGPRs
typedef __attribute__((ext_vector_type(4))) float f32x4;
typedef float v2f __attribute__((ext_vector_type(2)));

typedef __attribute__((address_space(3))) void lds_void;
typedef const __attribute__((address_space(1))) void gbl_void;

__device__ __forceinline__ unsigned short f2bf(float f) {
    __hip_bfloat16 h = __float2bfloat16(f);   // RTNE
    return *reinterpret_cast<unsigned short*>(&h);
}

// ---------------------------------------------------------------------------
// Kernel 0: f32 -> bf16 convert for BOTH vf and W in one dispatch.
// ---------------------------------------------------------------------------
__global__ __launch_bounds__(256) void cvt_all(
    const float* __restrict__ vf, const float* __restrict__ W,
    unsigned short* __restrict__ vfB, unsigned short* __restrict__ WB)
{
    const int bid = blockIdx.x;
    const float* src;
    unsigned short* dst;
    int i;
    if (bid < 1024) { src = vf; dst = vfB; i = (bid * 256 + threadIdx.x) * 8; }
    else           { src = W;  dst = WB;  i = ((bid - 1024) * 256 + threadIdx.x) * 8; }
    float4 v0 = *(const float4*)(src + i);
    float4 v1 = *(const float4*)(src + i + 4);
    bf16x8 o;
    o[0] = (short)f2bf(v0.x); o[1] = (short)f2bf(v0.y);
    o[2] = (short)f2bf(v0.z); o[3] = (short)f2bf(v0.w);
    o[4] = (short)f2bf(v1.x); o[5] = (short)f2bf(v1.y);
    o[6] = (short)f2bf(v1.z); o[7] = (short)f2bf(v1.w);
    *(bf16x8*)(dst + i) = o;
}

// ---------------------------------------------------------------------------
// Kernel 1: K-split GEMM (R5-proven pipeline) + ticket finisher that folds
// reduce_emb: last-of-4 ks blocks per (m0,n0) tile sums 4 pg planes + bias
// -> emb (same bytes as the standalone reduce, zero extra dispatch).
// grid (16,8,4) = 512 one-wave blocks = 2 blocks/CU.
// ---------------------------------------------------------------------------
__global__ __launch_bounds__(64) void gemm_lds(
    const unsigned short* __restrict__ vf,
    const unsigned short* __restrict__ W,
    const float* __restrict__ bias,
    float* __restrict__ part,                 // [KS, B, E] f32
    float* __restrict__ emb,                  // [B, E] f32
    int* __restrict__ tkG)                    // [128]
{
    __shared__ unsigned short sA[2][2048];
    __shared__ unsigned short sB[2][2048];
    __shared__ int lastFlag;

    const int L  = threadIdx.x;
    const int n0 = blockIdx.x * 64;
    const int m0 = blockIdx.y * 64;
    const int ks = blockIdx.z;

    const int subrow = L >> 2;
    const int qstg = (L & 3) ^ ((L >> 2) & 3) ^ ((L >> 4) & 3);
    const int kbeg = ks * KC;
    const unsigned short* aSrc[4];
    const unsigned short* bSrc[4];
    #pragma unroll
    for (int c = 0; c < 4; ++c) {
        aSrc[c] = vf + (size_t)(m0 + c * 16 + subrow) * D + kbeg + qstg * 8;
        bSrc[c] = W  + (size_t)(n0 + c * 16 + subrow) * D + kbeg + qstg * 8;
    }

    const int r16 = L & 15;
    const int quad = L >> 4;
    const int swz = quad ^ (r16 & 3) ^ ((r16 >> 2) & 3);
    const int aoff = r16 * 64 + swz * 16;

    f32x4 acc[4][4] = {};

    auto issue = [&](int step, int buf) {
        const size_t koff = (size_t)step * 32;
        #pragma unroll
        for (int c = 0; c < 4; ++c) {
            __builtin_amdgcn_global_load_lds(
                (gbl_void*)(aSrc[c] + koff),
                (lds_void*)((char*)&sA[buf][0] + c * 1024), 16, 0, 0);
            __builtin_amdgcn_global_load_lds(
                (gbl_void*)(bSrc[c] + koff),
                (lds_void*)((char*)&sB[buf][0] + c * 1024), 16, 0, 0);
        }
    };

    issue(0, 0);
    issue(1, 1);

    #pragma unroll 1
    for (int s = 0; s < NSTEP; ++s) {
        const int buf = s & 1;
        if (s == NSTEP - 1) __builtin_amdgcn_s_waitcnt(0x0F70);  // vmcnt(0)
        else                __builtin_amdgcn_s_waitcnt(0x0F78);  // vmcnt(8)

        bf16x8 af[4], bf_[4];
        #pragma unroll
        for (int i = 0; i < 4; ++i)
            af[i] = *(const bf16x8*)((const char*)&sA[buf][0] + i * 1024 + aoff);
        #pragma unroll
        for (int j = 0; j < 4; ++j)
            bf_[j] = *(const bf16x8*)((const char*)&sB[buf][0] + j * 1024 + aoff);

        #pragma unroll
        for (int i = 0; i < 4; ++i)
            #pragma unroll
            for (int j = 0; j < 4; ++j)
                acc[i][j] = __builtin_amdgcn_mfma_f32_16x16x32_bf16(
                    af[i], bf_[j], acc[i][j], 0, 0, 0);

        if (s + 2 < NSTEP) issue(s + 2, buf);
    }

    float* po = part + (size_t)ks * B * E;
    #pragma unroll
    for (int j = 0; j < 4; ++j) {
        const int col = n0 + j * 16 + r16;
        #pragma unroll
        for (int i = 0; i < 4; ++i) {
            const int row = m0 + i * 16 + quad * 4;
            #pragma unroll
            for (int r = 0; r < 4; ++r)
                po[(size_t)(row + r) * E + col] = acc[i][j][r];
        }
    }

    // ---- ticket finisher: fold reduce_emb for this 64x64 tile ----
    __syncthreads();                 // drain stores (single wave)
    __threadfence();                 // release: pg plane visible device-wide
    if (L == 0) lastFlag = (atomicAdd(&tkG[blockIdx.y * 16 + blockIdx.x], 1) == KS - 1);
    __syncthreads();
    if (lastFlag) {
        __threadfence();             // acquire: see other 3 planes
        const int col = n0 + (L & 15) * 4;
        const int rsub = L >> 4;
        float4 bv = *(const float4*)(bias + col);
        #pragma unroll
        for (int r = 0; r < 16; ++r) {
            const int row = m0 + rsub + 4 * r;
            float4 s = bv;
            #pragma unroll
            for (int z = 0; z < KS; ++z) {
                float4 p = *(const float4*)(part + (size_t)z * B * E + (size_t)row * E + col);
                s.x += p.x; s.y += p.y; s.z += p.z; s.w += p.w;
            }
            *(float4*)(emb + (size_t)row * E + col) = s;
        }
    }
}

// ---------------------------------------------------------------------------
// Kernel 2: fused scores (materialized emb). grid (9, 8, 8), 256 thr.
//  x<8 : neg tile (n0,b0) x e-plane z -> pn[z]; 8th block (ticket) sums
//        8 planes -> out[b][1+n] = -sqrt(s).
//  x==8: pos partial (b0, z) -> pp[z][b]; 8th -> out[b][0].
// ---------------------------------------------------------------------------
__global__ __launch_bounds__(256, 2) void scores_fused(
    const float* __restrict__ emb,    // [B, E]
    const float* __restrict__ n_lfs,  // [N, E]
    const float* __restrict__ p_lfs,  // [B, E]
    float* __restrict__ pn,           // [ES, B, N]
    float* __restrict__ pp,           // [ES, B]
    int* __restrict__ tkN,            // [64]
    int* __restrict__ tkP,            // [8]
    float* __restrict__ out)          // [B, 1+N]
{
    __shared__ float eS[64 * LDW];
    __shared__ float nS[64 * LDW];
    __shared__ int lastFlag;

    const int t   = threadIdx.x;
    const int b0i = blockIdx.y;
    const int z   = blockIdx.z;
    const int b0  = b0i * 64;
    const int e0  = z * EC;

    if (blockIdx.x == 8) {
        // ---------------- positive partials ----------------
        const int row = t >> 2;        // 0..63
        const int sub = t & 3;         // 4 threads/row, 32 e each
        const int b   = b0 + row;
        const int eb  = e0 + sub * 32;
        float acc = 0.f;
        #pragma unroll
        for (int q = 0; q < 8; ++q) {
            const int e = eb + q * 4;
            float4 v = *(const float4*)(emb + (size_t)b * E + e);
            float4 p = *(const float4*)(p_lfs + (size_t)b * E + e);
            float d;
            d = p.x - v.x; d = fmaxf(d, 0.f); acc = fmaf(d, d, acc);
            d = p.y - v.y; d = fmaxf(d, 0.f); acc = fmaf(d, d, acc);
            d = p.z - v.z; d = fmaxf(d, 0.f); acc = fmaf(d, d, acc);
            d = p.w - v.w; d = fmaxf(d, 0.f); acc = fmaf(d, d, acc);
        }
        acc += __shfl_down(acc, 2, 4);
        acc += __shfl_down(acc, 1, 4);
        if (sub == 0) pp[z * B + b] = acc;

        __syncthreads();
        __threadfence();                 // release
        if (t == 0) lastFlag = (atomicAdd(&tkP[b0i], 1) == ES - 1);
        __syncthreads();
        if (lastFlag) {
            __threadfence();             // acquire
            if (t < 64) {
                const int b2 = b0 + t;
                float s = 0.f;
                #pragma unroll
                for (int zz = 0; zz < ES; ++zz) s += pp[zz * B + b2];
                out[(size_t)b2 * 513] = -sqrtf(s);
            }
        }
        return;
    }

    // ---------------- negative tile ----------------
    const int n0 = blockIdx.x * 64;
    {
        const int row = t >> 2;            // 0..63
        const int cb  = (t & 3) * 32;      // 0,32,64,96
        const float* ep = emb   + (size_t)(b0 + row) * E + e0 + cb;
        const float* np = n_lfs + (size_t)(n0 + row) * E + e0 + cb;
        float* ed = &eS[row * LDW + cb];
        float* nd = &nS[row * LDW + cb];
        #pragma unroll
        for (int q = 0; q < 8; ++q) {
            float4 v  = *(const float4*)(ep + q * 4);
            float4 wv = *(const float4*)(np + q * 4);
            *(v2f*)(ed + q * 4)     = (v2f){v.x, v.y};
            *(v2f*)(ed + q * 4 + 2) = (v2f){v.z, v.w};
            *(v2f*)(nd + q * 4)     = (v2f){wv.x, wv.y};
            *(v2f*)(nd + q * 4 + 2) = (v2f){wv.z, wv.w};
        }
    }
    __syncthreads();

    const int ty = t >> 4;   // 0..15 -> b rows ty+16r
    const int tx = t & 15;   // 0..15 -> n rows tx+16c

    const v2f zv = {0.f, 0.f};
    v2f acc[4][4] = {{zv,zv,zv,zv},{zv,zv,zv,zv},{zv,zv,zv,zv},{zv,zv,zv,zv}};

    #pragma unroll 4
    for (int e = 0; e < EC; e += 2) {
        v2f a[4], c[4];
        #pragma unroll
        for (int r = 0; r < 4; ++r)
            a[r] = *(const v2f*)&eS[(ty + 16 * r) * LDW + e];
        #pragma unroll
        for (int q = 0; q < 4; ++q)
            c[q] = *(const v2f*)&nS[(tx + 16 * q) * LDW + e];
        #pragma unroll
        for (int r = 0; r < 4; ++r)
            #pragma unroll
            for (int q = 0; q < 4; ++q) {
                v2f d = c[q] - a[r];
                d = __builtin_elementwise_max(d, zv);
                acc[r][q] = __builtin_elementwise_fma(d, d, acc[r][q]);
            }
    }

    float* po = pn + (size_t)z * B * N;
    #pragma unroll
    for (int r = 0; r < 4; ++r) {
        const size_t ob = (size_t)(b0 + ty + 16 * r) * N;
        #pragma unroll
        for (int q = 0; q < 4; ++q)
            po[ob + n0 + tx + 16 * q] = acc[r][q].x + acc[r][q].y;
    }

    __syncthreads();
    __threadfence();                 // release
    if (t == 0) lastFlag = (atomicAdd(&tkN[b0i * 8 + blockIdx.x], 1) == ES - 1);
    __syncthreads();
    if (lastFlag) {
        __threadfence();             // acquire
        #pragma unroll
        for (int r = 0; r < 4; ++r) {
            const int b = b0 + ty + 16 * r;
            #pragma unroll
            for (int q = 0; q < 4; ++q) {
                const int n = n0 + tx + 16 * q;
                float s = 0.f;
                #pragma unroll
                for (int zz = 0; zz < ES; ++zz)
                    s += pn[(size_t)zz * B * N + (size_t)b * N + n];
                out[(size_t)b * 513 + 1 + n] = -sqrtf(s);
            }
        }
    }
}

extern "C" void kernel_launch(void* const* d_in, const int* in_sizes, int n_in,
                              void* d_out, int out_size, void* d_ws, size_t ws_size,
                              hipStream_t stream) {
    const float* vf    = (const float*)d_in[0];  // [512,4096] f32
    const float* p_lfs = (const float*)d_in[1];  // [512,1024] f32
    const float* n_lfs = (const float*)d_in[2];  // [512,1024] f32
    const float* W     = (const float*)d_in[3];  // [1024,4096] f32
    const float* bias  = (const float*)d_in[4];  // [1024] f32
    float* out = (float*)d_out;                  // [512,513] f32

    // ws: pg [0,8MB) | pn [8,16) | pp [16MB,+16KB) | tk [17MB,+800B)
    //     vfB [18,22) | WB [22,30) | emb [30,32)
    char* ws = (char*)d_ws;
    float*          pg  = (float*)ws;
    float*          pn  = (float*)(ws + ((size_t)8 << 20));
    float*          pp  = (float*)(ws + ((size_t)16 << 20));
    int*            tk  = (int*)  (ws + ((size_t)17 << 20));
    unsigned short* vfB = (unsigned short*)(ws + ((size_t)18 << 20));
    unsigned short* WB  = (unsigned short*)(ws + ((size_t)22 << 20));
    float*          emb = (float*)(ws + ((size_t)30 << 20));

    // tickets: [0,128) gemm tiles | [128,192) neg tiles | [192,200) pos
    hipMemsetAsync(tk, 0, 200 * sizeof(int), stream);

    cvt_all<<<3072, 256, 0, stream>>>(vf, W, vfB, WB);

    dim3 g1(E / 64, B / 64, KS);   // (16, 8, 4) = 512 one-wave blocks
    gemm_lds<<<g1, 64, 0, stream>>>(vfB, WB, bias, pg, emb, tk);

    dim3 g2(9, B / 64, ES);        // (9, 8, 8) = 576 blocks
    scores_fused<<<g2, 256, 0, stream>>>(emb, n_lfs, p_lfs, pn, pp,
                                         tk + 128, tk + 192, out);
}

// Round 10
// 161.807 us; speedup vs baseline: 1.7605x; 1.2485x over previous
//
#include <hip/hip_runtime.h>
#include <hip/hip_bf16.h>

// Problem constants (fixed by setup_inputs)
constexpr int B = 512;   // batch
constexpr int D = 4096;  // D_vis
constexpr int E = 1024;  // embed dim
constexpr int N = 512;   // negatives
constexpr int ES = 8;    // scores E-split factor
constexpr int EC = E / ES;      // 128 e per scores block
constexpr int LDW = EC + 2;     // 130

typedef __attribute__((ext_vector_type(8))) short bf16x8;   // 8 bf16 = 4 VGPRs
typedef __attribute__((ext_vector_type(4))) float f32x4;
typedef float v2f __attribute__((ext_vector_type(2)));

typedef __attribute__((address_space(3))) void lds_void;
typedef const __attribute__((address_space(1))) void gbl_void;

__device__ __forceinline__ unsigned short f2bf(float f) {
    __hip_bfloat16 h = __float2bfloat16(f);   // RTNE
    return *reinterpret_cast<unsigned short*>(&h);
}

// ---------------------------------------------------------------------------
// Kernel 0: f32 -> bf16 convert for BOTH vf and W in one dispatch.
// ---------------------------------------------------------------------------
__global__ __launch_bounds__(256) void cvt_all(
    const float* __restrict__ vf, const float* __restrict__ W,
    unsigned short* __restrict__ vfB, unsigned short* __restrict__ WB)
{
    const int bid = blockIdx.x;
    const float* src;
    unsigned short* dst;
    int i;
    if (bid < 1024) { src = vf; dst = vfB; i = (bid * 256 + threadIdx.x) * 8; }
    else           { src = W;  dst = WB;  i = ((bid - 1024) * 256 + threadIdx.x) * 8; }
    float4 v0 = *(const float4*)(src + i);
    float4 v1 = *(const float4*)(src + i + 4);
    bf16x8 o;
    o[0] = (short)f2bf(v0.x); o[1] = (short)f2bf(v0.y);
    o[2] = (short)f2bf(v0.z); o[3] = (short)f2bf(v0.w);
    o[4] = (short)f2bf(v1.x); o[5] = (short)f2bf(v1.y);
    o[6] = (short)f2bf(v1.z); o[7] = (short)f2bf(v1.w);
    *(bf16x8*)(dst + i) = o;
}

// ---------------------------------------------------------------------------
// Kernel 1: direct GEMM (KS=1): emb[b][e] = vf.W^T + bias, one 64x64 tile
// per wave, full K=4096 in 128 steps. Depth-4 global_load_lds pipeline
// (32 loads in flight, no barriers) + register-fragment double buffer so
// ds_reads of step s+1 hide under step-s MFMAs. grid (16,8) = 128 waves.
// Replaces R5's KS=4 gemm + pg round-trip + reduce_emb dispatch.
// LDS chunk swizzle identical to R5 (verified): (row,q) at
// row*64 + (q ^ (row&3) ^ ((row>>2)&3))*16 within each 4KB buffer.
// ---------------------------------------------------------------------------
__global__ __launch_bounds__(64) void gemm_direct(
    const unsigned short* __restrict__ vf,    // [B, D] bf16 bits
    const unsigned short* __restrict__ W,     // [E, D] bf16 bits
    const float* __restrict__ bias,           // [E]
    float* __restrict__ emb)                  // [B, E] f32
{
    __shared__ unsigned short sA[4][2048];    // 4 bufs x 64x32 bf16 (4KB each)
    __shared__ unsigned short sB[4][2048];

    const int L  = threadIdx.x;
    const int n0 = blockIdx.x * 64;
    const int m0 = blockIdx.y * 64;

    const int subrow = L >> 2;                                  // 0..15
    const int qstg = (L & 3) ^ ((L >> 2) & 3) ^ ((L >> 4) & 3);
    const unsigned short* aSrc[4];
    const unsigned short* bSrc[4];
    #pragma unroll
    for (int c = 0; c < 4; ++c) {
        aSrc[c] = vf + (size_t)(m0 + c * 16 + subrow) * D + qstg * 8;
        bSrc[c] = W  + (size_t)(n0 + c * 16 + subrow) * D + qstg * 8;
    }

    const int r16 = L & 15;
    const int quad = L >> 4;
    const int swz = quad ^ (r16 & 3) ^ ((r16 >> 2) & 3);
    const int aoff = r16 * 64 + swz * 16;   // byte offset within a 4KB buffer

    f32x4 acc[4][4] = {};

    auto issue = [&](int step) {
        const int buf = step & 3;
        const size_t koff = (size_t)step * 32;
        #pragma unroll
        for (int c = 0; c < 4; ++c) {
            __builtin_amdgcn_global_load_lds(
                (gbl_void*)(aSrc[c] + koff),
                (lds_void*)((char*)&sA[buf][0] + c * 1024), 16, 0, 0);
            __builtin_amdgcn_global_load_lds(
                (gbl_void*)(bSrc[c] + koff),
                (lds_void*)((char*)&sB[buf][0] + c * 1024), 16, 0, 0);
        }
    };

    bf16x8 a0[4], b0[4], a1[4], b1[4];

    auto readFrags = [&](int step, bf16x8* af, bf16x8* bf_) {
        const int buf = step & 3;
        #pragma unroll
        for (int i = 0; i < 4; ++i)
            af[i] = *(const bf16x8*)((const char*)&sA[buf][0] + i * 1024 + aoff);
        #pragma unroll
        for (int j = 0; j < 4; ++j)
            bf_[j] = *(const bf16x8*)((const char*)&sB[buf][0] + j * 1024 + aoff);
    };

    auto mfma16 = [&](bf16x8* af, bf16x8* bf_) {
        #pragma unroll
        for (int i = 0; i < 4; ++i)
            #pragma unroll
            for (int j = 0; j < 4; ++j)
                acc[i][j] = __builtin_amdgcn_mfma_f32_16x16x32_bf16(
                    af[i], bf_[j], acc[i][j], 0, 0, 0);
    };

    issue(0); issue(1); issue(2); issue(3);          // 32 loads in flight
    __builtin_amdgcn_s_waitcnt(0x4F78);              // vmcnt(24): buf0 ready
    readFrags(0, a0, b0);

    // Uniform pipeline: s = 0,2,...,122. Reads s+1,s+2; issues s+4,s+5 (<=127).
    // Before readFrags(k): issued through L -> vmcnt(8*(L-k)) = 16 here.
    #pragma unroll 1
    for (int s = 0; s < 124; s += 2) {
        __builtin_amdgcn_s_waitcnt(0x4F70);          // vmcnt(16): buf s+1 ready
        readFrags(s + 1, a1, b1);
        mfma16(a0, b0);
        issue(s + 4);
        __builtin_amdgcn_s_waitcnt(0x4F70);          // vmcnt(16): buf s+2 ready
        readFrags(s + 2, a0, b0);
        mfma16(a1, b1);
        issue(s + 5);
    }
    // Tail: s = 124, 126 (issued through 127).
    __builtin_amdgcn_s_waitcnt(0x4F70);              // vmcnt(16): buf125 ready
    readFrags(125, a1, b1);
    mfma16(a0, b0);                                  // step 124
    __builtin_amdgcn_s_waitcnt(0x0F78);              // vmcnt(8):  buf126 ready
    readFrags(126, a0, b0);
    mfma16(a1, b1);                                  // step 125
    __builtin_amdgcn_s_waitcnt(0x0F70);              // vmcnt(0):  buf127 ready
    readFrags(127, a1, b1);
    mfma16(a0, b0);                                  // step 126
    mfma16(a1, b1);                                  // step 127

    #pragma unroll
    for (int j = 0; j < 4; ++j) {
        const int col = n0 + j * 16 + r16;
        const float bv = bias[col];
        #pragma unroll
        for (int i = 0; i < 4; ++i) {
            const int row = m0 + i * 16 + quad * 4;
            #pragma unroll
            for (int r = 0; r < 4; ++r)
                emb[(size_t)(row + r) * E + col] = acc[i][j][r] + bv;
        }
    }
}

// ---------------------------------------------------------------------------
// Kernel 2: neg-score partials (R5-proven).
// grid (8,8,8) = 512 blocks = 2 blocks/CU. 64b x 64n tile, 4x4 v2f accs.
// ---------------------------------------------------------------------------
__global__ __launch_bounds__(256, 2) void scores_part(
    const float* __restrict__ emb,    // [B, E] f32
    const float* __restrict__ n_lfs,  // [N, E] f32
    float* __restrict__ pn)           // [ES, B, N] f32
{
    __shared__ float eS[64 * LDW];
    __shared__ float nS[64 * LDW];

    const int t  = threadIdx.x;
    const int n0 = blockIdx.x * 64;
    const int b0 = blockIdx.y * 64;
    const int e0 = blockIdx.z * EC;

    {
        const int row = t >> 2;            // 0..63
        const int cb  = (t & 3) * 32;      // 0,32,64,96
        const float* ep = emb   + (size_t)(b0 + row) * E + e0 + cb;
        const float* np = n_lfs + (size_t)(n0 + row) * E + e0 + cb;
        float* ed = &eS[row * LDW + cb];
        float* nd = &nS[row * LDW + cb];
        #pragma unroll
        for (int q = 0; q < 8; ++q) {
            float4 v = *(const float4*)(ep + q * 4);
            float4 w = *(const float4*)(np + q * 4);
            *(v2f*)(ed + q * 4)     = (v2f){v.x, v.y};
            *(v2f*)(ed + q * 4 + 2) = (v2f){v.z, v.w};
            *(v2f*)(nd + q * 4)     = (v2f){w.x, w.y};
            *(v2f*)(nd + q * 4 + 2) = (v2f){w.z, w.w};
        }
    }
    __syncthreads();

    const int ty = t >> 4;   // 0..15 -> b rows ty+16r
    const int tx = t & 15;   // 0..15 -> n rows tx+16c

    const v2f z = {0.f, 0.f};
    v2f acc[4][4] = {{z,z,z,z},{z,z,z,z},{z,z,z,z},{z,z,z,z}};

    #pragma unroll 4
    for (int e = 0; e < EC; e += 2) {
        v2f a[4], c[4];
        #pragma unroll
        for (int r = 0; r < 4; ++r)
            a[r] = *(const v2f*)&eS[(ty + 16 * r) * LDW + e];
        #pragma unroll
        for (int q = 0; q < 4; ++q)
            c[q] = *(const v2f*)&nS[(tx + 16 * q) * LDW + e];
        #pragma unroll
        for (int r = 0; r < 4; ++r)
            #pragma unroll
            for (int q = 0; q < 4; ++q) {
                v2f d = c[q] - a[r];
                d = __builtin_elementwise_max(d, z);
                acc[r][q] = __builtin_elementwise_fma(d, d, acc[r][q]);
            }
    }

    float* po = pn + (size_t)blockIdx.z * B * N;
    #pragma unroll
    for (int r = 0; r < 4; ++r) {
        const size_t ob = (size_t)(b0 + ty + 16 * r) * N;
        #pragma unroll
        for (int q = 0; q < 4; ++q)
            po[ob + n0 + tx + 16 * q] = acc[r][q].x + acc[r][q].y;
    }
}

// ---------------------------------------------------------------------------
// Kernel 3: final scores (negatives reduce + positive scores). R5-proven.
// ---------------------------------------------------------------------------
__global__ __launch_bounds__(256) void scores_final(
    const float* __restrict__ pn,     // [ES, B, N]
    const float* __restrict__ emb,    // [B, E]
    const float* __restrict__ p_lfs,  // [B, E]
    float* __restrict__ out)          // [B, 1+N]
{
    const int t = threadIdx.x;
    if (blockIdx.x < 1024) {
        const int i = blockIdx.x * 256 + t;       // 0..B*N-1
        const int b = i >> 9;
        const int n = i & (N - 1);
        float s = 0.f;
        #pragma unroll
        for (int z = 0; z < ES; ++z)
            s += pn[(size_t)z * B * N + i];
        out[(size_t)b * 513 + 1 + n] = -sqrtf(s);
        return;
    }
    const int b0 = (blockIdx.x - 1024) * 32;
    const int r = t >> 3;        // 0..31
    const int g = t & 7;         // 8 threads per row
    const float* pr = p_lfs + (size_t)(b0 + r) * E;
    const float* er = emb   + (size_t)(b0 + r) * E;
    float acc = 0.f;
    for (int e = g * 4; e < E; e += 32) {
        float4 p = *(const float4*)(pr + e);
        float4 v = *(const float4*)(er + e);
        float d;
        d = p.x - v.x; d = fmaxf(d, 0.f); acc = fmaf(d, d, acc);
        d = p.y - v.y; d = fmaxf(d, 0.f); acc = fmaf(d, d, acc);
        d = p.z - v.z; d = fmaxf(d, 0.f); acc = fmaf(d, d, acc);
        d = p.w - v.w; d = fmaxf(d, 0.f); acc = fmaf(d, d, acc);
    }
    #pragma unroll
    for (int off = 4; off; off >>= 1) acc += __shfl_down(acc, off, 8);
    if (g == 0) out[(size_t)(b0 + r) * 513] = -sqrtf(acc);
}

extern "C" void kernel_launch(void* const* d_in, const int* in_sizes, int n_in,
                              void* d_out, int out_size, void* d_ws, size_t ws_size,
                              hipStream_t stream) {
    const float* vf    = (const float*)d_in[0];  // [512,4096] f32
    const float* p_lfs = (const float*)d_in[1];  // [512,1024] f32
    const float* n_lfs = (const float*)d_in[2];  // [512,1024] f32
    const float* W     = (const float*)d_in[3];  // [1024,4096] f32
    const float* bias  = (const float*)d_in[4];  // [1024] f32
    float* out = (float*)d_out;                  // [512,513] f32

    // ws: pn [0,8MB) | vfB [8,12) | WB [12,20) | emb [20,22)
    char* ws = (char*)d_ws;
    float*          pn  = (float*)ws;
    unsigned short* vfB = (unsigned short*)(ws + ((size_t)8 << 20));
    unsigned short* WB  = (unsigned short*)(ws + ((size_t)12 << 20));
    float*          emb = (float*)(ws + ((size_t)20 << 20));

    cvt_all<<<3072, 256, 0, stream>>>(vf, W, vfB, WB);

    dim3 g1(E / 64, B / 64);       // (16, 8) = 128 one-wave blocks
    gemm_direct<<<g1, 64, 0, stream>>>(vfB, WB, bias, emb);

    dim3 g3(N / 64, B / 64, ES);   // (8, 8, 8) = 512 blocks
    scores_part<<<g3, 256, 0, stream>>>(emb, n_lfs, pn);

    scores_final<<<1024 + B / 32, 256, 0, stream>>>(pn, emb, p_lfs, out);
}